// Round 2
// baseline (1678.866 us; speedup 1.0000x reference)
//
#include <hip/hip_runtime.h>
#include <cstddef>

// ---------------- problem constants ----------------
#define B_   32
#define C_   384
#define HW_  3136      // 56*56
#define NTOK 100352    // B*H*W
#define NWIN 2048      // B * 8*8
#define NH_  12
#define SCALE_ 0.17677669529663687f  // 1/sqrt(32)

typedef __attribute__((ext_vector_type(8))) short bf16x8;
typedef __attribute__((ext_vector_type(4))) float f32x4;

__device__ __forceinline__ unsigned short f2bf(float f) {
    unsigned int u = __builtin_bit_cast(unsigned int, f);
    u = (u + 0x7FFFu + ((u >> 16) & 1u)) >> 16;
    return (unsigned short)u;
}
__device__ __forceinline__ float bf2f(unsigned short h) {
    unsigned int u = ((unsigned int)h) << 16;
    return __builtin_bit_cast(float, u);
}

// ---------------- K0: weight cast+transpose  W[K][N] -> Wt[N][K] bf16 ----------------
__global__ __launch_bounds__(256) void k_wt(const float* __restrict__ W,
                                            unsigned short* __restrict__ Wt,
                                            int K, int N) {
    int idx = blockIdx.x * 256 + threadIdx.x;
    if (idx >= N * K) return;
    int n = idx / K, k = idx - n * K;
    Wt[idx] = f2bf(W[(size_t)k * N + n]);
}

// ---------------- K1: per-pixel mean/rstd over C (LN1 stats) ----------------
__global__ __launch_bounds__(256) void k_meanvar(const float* __restrict__ x,
                                                 float* __restrict__ mean,
                                                 float* __restrict__ rstd) {
    int p = blockIdx.x * 256 + threadIdx.x;      // < NTOK, exact
    int b = p / HW_, hw = p - b * HW_;
    const float* xp = x + (size_t)b * C_ * HW_ + hw;
    float s = 0.f, sq = 0.f;
    for (int c = 0; c < C_; ++c) { float v = xp[(size_t)c * HW_]; s += v; sq += v * v; }
    float m = s * (1.0f / C_);
    float var = sq * (1.0f / C_) - m * m;
    mean[p] = m;
    rstd[p] = rsqrtf(var + 1e-5f);
}

// ---------------- K2: transpose + shift + window-gather + LN1 ----------------
__global__ __launch_bounds__(256) void k_ln1_gather(const float* __restrict__ x,
        const float* __restrict__ mean, const float* __restrict__ rstd,
        const float* __restrict__ g1, const float* __restrict__ b1,
        unsigned short* __restrict__ xw, unsigned short* __restrict__ xs) {
    __shared__ float T[32][33];
    int b = blockIdx.z, hw0 = blockIdx.y * 32, c0 = blockIdx.x * 32;
    int tid = threadIdx.x, lo = tid & 31, hi = tid >> 5;
    #pragma unroll
    for (int p = 0; p < 4; ++p) {
        int cr = hi + p * 8;   // c-local
        T[cr][lo] = x[((size_t)b * C_ + c0 + cr) * HW_ + hw0 + lo];
    }
    __syncthreads();
    #pragma unroll
    for (int p = 0; p < 4; ++p) {
        int row = hi + p * 8;          // hw-local
        int hw = hw0 + row;
        int hs = hw / 56, wsrc = hw - hs * 56;
        int h = hs + 53; if (h >= 56) h -= 56;   // shifted-image coords
        int w = wsrc + 53; if (w >= 56) w -= 56;
        size_t t1 = ((size_t)b * 64 + (h / 7) * 8 + (w / 7)) * 49 + (h % 7) * 7 + (w % 7);
        float m = mean[b * HW_ + hw], rs = rstd[b * HW_ + hw];
        int c = c0 + lo;
        float v = T[lo][row];
        xw[t1 * C_ + c] = f2bf((v - m) * rs * g1[c] + b1[c]);
        xs[t1 * C_ + c] = f2bf(v);
    }
}

// ---------------- MFMA GEMM: C[M][N] = A[M][K] * Bt[N][K]^T + bias
// mode 0: bf16 out   mode 1: gelu(erf)->bf16   mode 2: qk passthrough + v transpose-scatter
__global__ __launch_bounds__(256) void k_gemm(const unsigned short* __restrict__ A,
        const unsigned short* __restrict__ Bt, const float* __restrict__ bias,
        unsigned short* __restrict__ out, int M, int N, int K, int mode,
        unsigned short* __restrict__ vo) {
    __shared__ unsigned short As[128][40];   // +8 pad for conflict-reduced b128 reads
    __shared__ unsigned short Bs[128][40];
    int tid = threadIdx.x;
    int lane = tid & 63, wave = tid >> 6;
    int l15 = lane & 15, quad = lane >> 4;
    int wr = wave >> 1, wc = wave & 1;
    size_t mt = blockIdx.y, nt = blockIdx.x;
    int srow = tid >> 2, scol = (tid & 3) * 8;
    const unsigned short* Ab = A + mt * 128 * (size_t)K;
    const unsigned short* Bb = Bt + nt * 128 * (size_t)K;
    f32x4 z = {0.f, 0.f, 0.f, 0.f};
    f32x4 acc[4][4];
    #pragma unroll
    for (int i = 0; i < 4; ++i)
        #pragma unroll
        for (int j = 0; j < 4; ++j) acc[i][j] = z;

    for (int k0 = 0; k0 < K; k0 += 32) {
        *(uint4*)&As[srow][scol]    = *(const uint4*)(Ab + (size_t)srow * K + k0 + scol);
        *(uint4*)&As[srow+64][scol] = *(const uint4*)(Ab + (size_t)(srow+64) * K + k0 + scol);
        *(uint4*)&Bs[srow][scol]    = *(const uint4*)(Bb + (size_t)srow * K + k0 + scol);
        *(uint4*)&Bs[srow+64][scol] = *(const uint4*)(Bb + (size_t)(srow+64) * K + k0 + scol);
        __syncthreads();
        bf16x8 af[4], bfr[4];
        #pragma unroll
        for (int mi = 0; mi < 4; ++mi) af[mi] = *(const bf16x8*)&As[wr*64 + mi*16 + l15][quad*8];
        #pragma unroll
        for (int ni = 0; ni < 4; ++ni) bfr[ni] = *(const bf16x8*)&Bs[wc*64 + ni*16 + l15][quad*8];
        #pragma unroll
        for (int mi = 0; mi < 4; ++mi)
            #pragma unroll
            for (int ni = 0; ni < 4; ++ni)
                acc[mi][ni] = __builtin_amdgcn_mfma_f32_16x16x32_bf16(af[mi], bfr[ni], acc[mi][ni], 0, 0, 0);
        __syncthreads();
    }

    int mb = (int)mt * 128 + wr * 64, nb = (int)nt * 128 + wc * 64;
    #pragma unroll
    for (int mi = 0; mi < 4; ++mi)
        #pragma unroll
        for (int ni = 0; ni < 4; ++ni) {
            int gc = nb + ni * 16 + l15;
            float bv = bias[gc];
            #pragma unroll
            for (int r = 0; r < 4; ++r) {
                int gr = mb + mi * 16 + quad * 4 + r;
                float v = acc[mi][ni][r] + bv;
                if (mode == 0) {
                    out[(size_t)gr * N + gc] = f2bf(v);
                } else if (mode == 1) {
                    v = 0.5f * v * (1.0f + erff(v * 0.70710678118654752f));
                    out[(size_t)gr * N + gc] = f2bf(v);
                } else {
                    if (gc < 768) {
                        out[(size_t)gr * 768 + gc] = f2bf(v);   // q,k in [t1][768]
                    } else {
                        int rem = gc - 768;
                        int head = rem >> 5, hd = rem & 31;
                        int win = gr / 49, tok = gr - win * 49;
                        vo[(((size_t)win * NH_ + head) * 32 + hd) * 64 + tok] = f2bf(v);
                    }
                }
            }
        }
}

// ---------------- K4: windowed attention, one wave per (window, head) ----------------
__global__ __launch_bounds__(256) void k_attn(const unsigned short* __restrict__ qk,
        const unsigned short* __restrict__ vtb, const float* __restrict__ rpb,
        unsigned short* __restrict__ o) {
    __shared__ unsigned short P[4][64][72];   // wave-private slices
    int tid = threadIdx.x;
    int wave = tid >> 6, lane = tid & 63, l15 = lane & 15, quad = lane >> 4;
    int win = blockIdx.x / 3;
    int head = (blockIdx.x % 3) * 4 + wave;
    int wi = win & 63, wh = wi >> 3, ww = wi & 7;
    const unsigned short* qh = qk + (size_t)win * 49 * 768 + head * 32;
    const unsigned short* kh = qh + 384;
    const unsigned short* vh = vtb + ((size_t)win * NH_ + head) * (32 * 64);

    bf16x8 qf[4], kf[4];
    #pragma unroll
    for (int mi = 0; mi < 4; ++mi) qf[mi] = *(const bf16x8*)(qh + (size_t)(mi * 16 + l15) * 768 + quad * 8);
    #pragma unroll
    for (int ni = 0; ni < 4; ++ni) kf[ni] = *(const bf16x8*)(kh + (size_t)(ni * 16 + l15) * 768 + quad * 8);

    f32x4 z = {0.f, 0.f, 0.f, 0.f};
    f32x4 s[4][4];
    #pragma unroll
    for (int mi = 0; mi < 4; ++mi)
        #pragma unroll
        for (int ni = 0; ni < 4; ++ni)
            s[mi][ni] = __builtin_amdgcn_mfma_f32_16x16x32_bf16(qf[mi], kf[ni], z, 0, 0, 0);

    // scale + rel-pos bias + shift mask; pad -> -1e30
    #pragma unroll
    for (int mi = 0; mi < 4; ++mi)
        #pragma unroll
        for (int r = 0; r < 4; ++r) {
            int qr = mi * 16 + quad * 4 + r;
            int qi = qr / 7, qj = qr - qi * 7;
            int rqh = (wh == 7) ? (qi < 4 ? 1 : 2) : 0;
            int rqw = (ww == 7) ? (qj < 4 ? 1 : 2) : 0;
            #pragma unroll
            for (int ni = 0; ni < 4; ++ni) {
                int kcol = ni * 16 + l15;
                float v = s[mi][ni][r] * SCALE_;
                if (qr < 49 && kcol < 49) {
                    int ki = kcol / 7, kj = kcol - ki * 7;
                    int idx = (qi - ki + 6) * 13 + (qj - kj + 6);
                    v += rpb[idx * NH_ + head];
                    int rkh = (wh == 7) ? (ki < 4 ? 1 : 2) : 0;
                    int rkw = (ww == 7) ? (kj < 4 ? 1 : 2) : 0;
                    if ((rqh * 3 + rqw) != (rkh * 3 + rkw)) v -= 100.0f;
                } else v = -1e30f;
                s[mi][ni][r] = v;
            }
        }

    // softmax per query row (row = 16 lanes of one quad, across 4 ni-tiles)
    float rinv[4][4];
    #pragma unroll
    for (int mi = 0; mi < 4; ++mi)
        #pragma unroll
        for (int r = 0; r < 4; ++r) {
            float m = fmaxf(fmaxf(s[mi][0][r], s[mi][1][r]), fmaxf(s[mi][2][r], s[mi][3][r]));
            #pragma unroll
            for (int d = 1; d < 16; d <<= 1) m = fmaxf(m, __shfl_xor(m, d));
            float sum = 0.f;
            #pragma unroll
            for (int ni = 0; ni < 4; ++ni) {
                float p = __expf(s[mi][ni][r] - m);
                s[mi][ni][r] = p;
                sum += p;
            }
            #pragma unroll
            for (int d = 1; d < 16; d <<= 1) sum += __shfl_xor(sum, d);
            rinv[mi][r] = 1.0f / sum;
        }

    // P: MFMA C-layout -> LDS -> A-layout
    #pragma unroll
    for (int mi = 0; mi < 4; ++mi)
        #pragma unroll
        for (int ni = 0; ni < 4; ++ni)
            #pragma unroll
            for (int r = 0; r < 4; ++r)
                P[wave][mi * 16 + quad * 4 + r][ni * 16 + l15] = f2bf(s[mi][ni][r]);
    __syncthreads();

    f32x4 oacc[4][2];
    #pragma unroll
    for (int mi = 0; mi < 4; ++mi) { oacc[mi][0] = z; oacc[mi][1] = z; }
    #pragma unroll
    for (int kt = 0; kt < 2; ++kt) {
        bf16x8 vf[2];
        #pragma unroll
        for (int n2 = 0; n2 < 2; ++n2)
            vf[n2] = *(const bf16x8*)(vh + (n2 * 16 + l15) * 64 + kt * 32 + quad * 8);
        #pragma unroll
        for (int mi = 0; mi < 4; ++mi) {
            bf16x8 pf = *(const bf16x8*)&P[wave][mi * 16 + l15][kt * 32 + quad * 8];
            #pragma unroll
            for (int n2 = 0; n2 < 2; ++n2)
                oacc[mi][n2] = __builtin_amdgcn_mfma_f32_16x16x32_bf16(pf, vf[n2], oacc[mi][n2], 0, 0, 0);
        }
    }

    #pragma unroll
    for (int mi = 0; mi < 4; ++mi)
        #pragma unroll
        for (int r = 0; r < 4; ++r) {
            int qr = mi * 16 + quad * 4 + r;
            if (qr < 49) {
                float sc = rinv[mi][r];
                #pragma unroll
                for (int n2 = 0; n2 < 2; ++n2)
                    o[((size_t)win * 49 + qr) * C_ + head * 32 + n2 * 16 + l15] =
                        f2bf(oacc[mi][n2][r] * sc);
            }
        }
}

// ---------------- K5: residual add + LN2 (one wave per token), no fp32 resid store ----------------
__global__ __launch_bounds__(256) void k_resid_ln2(const unsigned short* __restrict__ proj,
        const unsigned short* __restrict__ xs, const float* __restrict__ g2,
        const float* __restrict__ b2, unsigned short* __restrict__ xn2) {
    int wave = threadIdx.x >> 6, lane = threadIdx.x & 63;
    size_t t = (size_t)blockIdx.x * 4 + wave;
    const unsigned short* pp = proj + t * C_;
    const unsigned short* sp = xs + t * C_;
    float v[6];
    float sum = 0.f, sq = 0.f;
    #pragma unroll
    for (int j = 0; j < 6; ++j) {
        int c = j * 64 + lane;
        float val = bf2f(pp[c]) + bf2f(sp[c]);
        v[j] = val; sum += val; sq += val * val;
    }
    #pragma unroll
    for (int d = 1; d < 64; d <<= 1) { sum += __shfl_xor(sum, d); sq += __shfl_xor(sq, d); }
    float m = sum * (1.0f / C_);
    float rs = rsqrtf(sq * (1.0f / C_) - m * m + 1e-5f);
    #pragma unroll
    for (int j = 0; j < 6; ++j) {
        int c = j * 64 + lane;
        xn2[t * C_ + c] = f2bf((v[j] - m) * rs * g2[c] + b2[c]);
    }
}

// ---------------- K7: final sum (xs+prj+mlp) + un-shift + transpose to (B,C,H,W) ----------------
__global__ __launch_bounds__(256) void k_final(const unsigned short* __restrict__ xs,
        const unsigned short* __restrict__ prj, const unsigned short* __restrict__ mlp,
        float* __restrict__ out) {
    __shared__ float T[32][33];
    int b = blockIdx.z, hw0 = blockIdx.y * 32, c0 = blockIdx.x * 32;
    int tid = threadIdx.x, lo = tid & 31, hi = tid >> 5;
    #pragma unroll
    for (int p = 0; p < 4; ++p) {
        int row = hi + p * 8;          // hw-local (output coords)
        int hw = hw0 + row;
        int ho = hw / 56, wo = hw - ho * 56;
        int h = ho + 53; if (h >= 56) h -= 56;
        int w = wo + 53; if (w >= 56) w -= 56;
        size_t t1 = ((size_t)b * 64 + (h / 7) * 8 + (w / 7)) * 49 + (h % 7) * 7 + (w % 7);
        int c = c0 + lo;
        T[row][lo] = bf2f(xs[t1 * C_ + c]) + bf2f(prj[t1 * C_ + c]) + bf2f(mlp[t1 * C_ + c]);
    }
    __syncthreads();
    #pragma unroll
    for (int p = 0; p < 4; ++p) {
        int cr = hi + p * 8;
        out[((size_t)b * C_ + c0 + cr) * HW_ + hw0 + lo] = T[lo][cr];
    }
}

// ---------------- launch ----------------
extern "C" void kernel_launch(void* const* d_in, const int* in_sizes, int n_in,
                              void* d_out, int out_size, void* d_ws, size_t ws_size,
                              hipStream_t stream) {
    const float* x      = (const float*)d_in[0];
    const float* qkv_w  = (const float*)d_in[1];
    const float* qkv_b  = (const float*)d_in[2];
    const float* proj_w = (const float*)d_in[3];
    const float* proj_b = (const float*)d_in[4];
    const float* rpb    = (const float*)d_in[5];
    const float* n1w    = (const float*)d_in[6];
    const float* n1b    = (const float*)d_in[7];
    const float* n2w    = (const float*)d_in[8];
    const float* n2b    = (const float*)d_in[9];
    const float* fc1w   = (const float*)d_in[10];
    const float* fc1b   = (const float*)d_in[11];
    const float* fc2w   = (const float*)d_in[12];
    const float* fc2b   = (const float*)d_in[13];
    float* out = (float*)d_out;
    (void)ws_size; (void)in_sizes; (void)n_in; (void)out_size;

    // ---- workspace layout with lifetime-based aliasing (~394 MB total) ----
    char* ws = (char*)d_ws;
    size_t off = 0;
    auto take = [&](size_t bytes) -> char* {
        char* p = ws + off;
        off = (off + bytes + 255) & ~((size_t)255);
        return p;
    };
    const size_t SZ_TC = (size_t)NTOK * C_ * 2;              // 77,070,336
    unsigned short* xs   = (unsigned short*)take(SZ_TC);                   // live: gather -> final
    unsigned short* bufB = (unsigned short*)take(SZ_TC);                   // xw -> ob -> hid chunks
    unsigned short* bufC = (unsigned short*)take((size_t)(NTOK + 16) * 768 * 2); // qk -> prj+xn2
    unsigned short* bufD = (unsigned short*)take((size_t)NWIN * NH_ * 32 * 64 * 2); // vt -> mlp
    float* meanb = (float*)take((size_t)NTOK * 4);
    float* rstdb = (float*)take((size_t)NTOK * 4);
    unsigned short* wqkv = (unsigned short*)take((size_t)1152 * 384 * 2);
    unsigned short* wprj = (unsigned short*)take((size_t)384 * 384 * 2);
    unsigned short* wfc1 = (unsigned short*)take((size_t)1536 * 384 * 2);
    unsigned short* wfc2 = (unsigned short*)take((size_t)384 * 1536 * 2);

    unsigned short* xw  = bufB;
    unsigned short* ob  = bufB;
    unsigned short* hid = bufB;                 // 4-chunk hidden: 25088*1536*2 = 77,070,336
    unsigned short* qkb = bufC;
    unsigned short* prj = bufC;
    unsigned short* xn2 = bufC + (SZ_TC / 2);   // offset in elements
    unsigned short* vt  = bufD;
    unsigned short* mlp = bufD;

    k_wt<<<(1152 * 384 + 255) / 256, 256, 0, stream>>>(qkv_w, wqkv, 384, 1152);
    k_wt<<<(384 * 384 + 255) / 256, 256, 0, stream>>>(proj_w, wprj, 384, 384);
    k_wt<<<(1536 * 384 + 255) / 256, 256, 0, stream>>>(fc1w, wfc1, 384, 1536);
    k_wt<<<(384 * 1536 + 255) / 256, 256, 0, stream>>>(fc2w, wfc2, 1536, 384);

    k_meanvar<<<NTOK / 256, 256, 0, stream>>>(x, meanb, rstdb);
    k_ln1_gather<<<dim3(12, 98, 32), 256, 0, stream>>>(x, meanb, rstdb, n1w, n1b, xw, xs);

    // QKV: writes q,k -> qkb[t1][768], v -> vt[win,head][hd][tok]
    k_gemm<<<dim3(1152 / 128, NTOK / 128), 256, 0, stream>>>(xw, wqkv, qkv_b, qkb,
            NTOK, 1152, 384, 2, vt);
    k_attn<<<NWIN * 3, 256, 0, stream>>>(qkb, vt, rpb, ob);
    k_gemm<<<dim3(384 / 128, NTOK / 128), 256, 0, stream>>>(ob, wprj, proj_b, prj,
            NTOK, 384, 384, 0, nullptr);
    k_resid_ln2<<<NTOK / 4, 256, 0, stream>>>(prj, xs, n2w, n2b, xn2);

    // MLP in 4 token-chunks so hid fits bufB (exactly 77,070,336 B per chunk)
    const int CH = NTOK / 4;   // 25088
    for (int i = 0; i < 4; ++i) {
        k_gemm<<<dim3(1536 / 128, CH / 128), 256, 0, stream>>>(
                xn2 + (size_t)i * CH * 384, wfc1, fc1b, hid, CH, 1536, 384, 1, nullptr);
        k_gemm<<<dim3(384 / 128, CH / 128), 256, 0, stream>>>(
                hid, wfc2, fc2b, mlp + (size_t)i * CH * 384, CH, 384, 1536, 0, nullptr);
    }
    k_final<<<dim3(12, 98, 32), 256, 0, stream>>>(xs, prj, mlp, out);
}

// Round 3
// 1358.884 us; speedup vs baseline: 1.2355x; 1.2355x over previous
//
#include <hip/hip_runtime.h>
#include <cstddef>

#define B_   32
#define C_   384
#define HW_  3136
#define NTOK 100352
#define NWIN 2048
#define NH_  12
#define SCALE_ 0.17677669529663687f

typedef __attribute__((ext_vector_type(8))) short bf16x8;
typedef __attribute__((ext_vector_type(4))) float f32x4;

__device__ __forceinline__ unsigned short f2bf(float f) {
    unsigned int u = __builtin_bit_cast(unsigned int, f);
    u = (u + 0x7FFFu + ((u >> 16) & 1u)) >> 16;
    return (unsigned short)u;
}
__device__ __forceinline__ float bf2f(unsigned short h) {
    unsigned int u = ((unsigned int)h) << 16;
    return __builtin_bit_cast(float, u);
}
__device__ __forceinline__ void gll16(const void* g, void* l) {
    __builtin_amdgcn_global_load_lds(
        (const __attribute__((address_space(1))) void*)g,
        (__attribute__((address_space(3))) void*)l, 16, 0, 0);
}

// ---------------- K0: weight cast+transpose  W[K][N] -> Wt[N][K] bf16 ----------------
__global__ __launch_bounds__(256) void k_wt(const float* __restrict__ W,
                                            unsigned short* __restrict__ Wt,
                                            int K, int N) {
    int idx = blockIdx.x * 256 + threadIdx.x;
    if (idx >= N * K) return;
    int n = idx / K, k = idx - n * K;
    Wt[idx] = f2bf(W[(size_t)k * N + n]);
}

// ---------------- K1: fused transpose + LN1 stats + shift/window-gather ----------------
__global__ __launch_bounds__(256) void k_ln1(const float* __restrict__ x,
        const float* __restrict__ g1, const float* __restrict__ b1,
        unsigned short* __restrict__ xw, unsigned short* __restrict__ xs) {
    __shared__ float T[384 * 33];
    __shared__ float Ps[8][32], Pq[8][32];
    __shared__ float Ms[32], Rs[32];
    __shared__ int T1s[32];
    int b = blockIdx.x / 98, strip = blockIdx.x - b * 98;
    int hw0 = strip * 32;
    int t = threadIdx.x;
    const float* xb = x + (size_t)b * (C_ * HW_) + hw0;
    #pragma unroll
    for (int j = 0; j < 48; ++j) {
        int flat = j * 256 + t;
        int c = flat >> 5, pix = flat & 31;
        T[c * 33 + pix] = xb[(size_t)c * HW_ + pix];
    }
    __syncthreads();
    {
        int pix = t & 31, ch = t >> 5;
        float s = 0.f, q = 0.f;
        #pragma unroll
        for (int c = ch * 48; c < ch * 48 + 48; ++c) { float v = T[c * 33 + pix]; s += v; q += v * v; }
        Ps[ch][pix] = s; Pq[ch][pix] = q;
    }
    __syncthreads();
    if (t < 32) {
        float s = 0.f, q = 0.f;
        #pragma unroll
        for (int ch = 0; ch < 8; ++ch) { s += Ps[ch][t]; q += Pq[ch][t]; }
        float m = s * (1.0f / C_);
        Ms[t] = m;
        Rs[t] = rsqrtf(q * (1.0f / C_) - m * m + 1e-5f);
        int hw = hw0 + t;
        int hs = hw / 56, wsrc = hw - hs * 56;
        int h = hs + 53; if (h >= 56) h -= 56;
        int w = wsrc + 53; if (w >= 56) w -= 56;
        T1s[t] = (b * 64 + (h / 7) * 8 + (w / 7)) * 49 + (h % 7) * 7 + (w % 7);
    }
    __syncthreads();
    #pragma unroll
    for (int j = 0; j < 48; ++j) {
        int flat = j * 256 + t;
        int pix = flat / C_, c = flat - pix * C_;
        float v = T[c * 33 + pix];
        size_t o = (size_t)T1s[pix] * C_ + c;
        xw[o] = f2bf((v - Ms[pix]) * Rs[pix] * g1[c] + b1[c]);
        xs[o] = f2bf(v);
    }
}

// ---------------- MFMA GEMM (m97-style staging + LDS-transposed epilogue) ----------------
__global__ __launch_bounds__(256) void k_gemm(const unsigned short* __restrict__ A,
        const unsigned short* __restrict__ Bt, const float* __restrict__ bias,
        unsigned short* __restrict__ out, int NT, int K, int ldout, int mode,
        unsigned short* __restrict__ vo) {
    __shared__ unsigned short smem[17408];   // Ct[128][136]; As=[0:4096), Bs=[4096:8192)
    unsigned short* As = smem;
    unsigned short* Bs = smem + 4096;
    int tid = threadIdx.x;
    int lane = tid & 63, wave = tid >> 6;
    int l15 = lane & 15, quad = lane >> 4;
    int wr = wave >> 1, wc = wave & 1;

    int flat = blockIdx.x;
    int xcd = flat & 7, s = flat >> 3;
    int nt = s % NT, mtg = s / NT;
    int mt = mtg * 8 + xcd;

    size_t K2 = (size_t)K * 2;
    const char* Ab = (const char*)A + (size_t)mt * 128 * K2;
    const char* Bb = (const char*)Bt + (size_t)nt * 128 * K2;
    int r0 = wave * 32 + (lane >> 2);
    int cb = (lane & 3) * 16;
    const char* gA0 = Ab + (size_t)r0 * K2 + cb;
    const char* gA1 = Ab + (size_t)(r0 + 16) * K2 + cb;
    const char* gB0 = Bb + (size_t)r0 * K2 + cb;
    const char* gB1 = Bb + (size_t)(r0 + 16) * K2 + cb;
    unsigned short* lA0 = As + wave * 1024;
    unsigned short* lA1 = As + wave * 1024 + 512;
    unsigned short* lB0 = Bs + wave * 1024;
    unsigned short* lB1 = Bs + wave * 1024 + 512;

    f32x4 z = {0.f, 0.f, 0.f, 0.f};
    f32x4 acc[4][4];
    #pragma unroll
    for (int i = 0; i < 4; ++i)
        #pragma unroll
        for (int j = 0; j < 4; ++j) acc[i][j] = z;

    int kiters = K >> 5;
    for (int ki = 0; ki < kiters; ++ki) {
        gll16(gA0, lA0); gll16(gA1, lA1); gll16(gB0, lB0); gll16(gB1, lB1);
        gA0 += 64; gA1 += 64; gB0 += 64; gB1 += 64;
        __syncthreads();
        bf16x8 af[4], bfr[4];
        #pragma unroll
        for (int mi = 0; mi < 4; ++mi) af[mi] = *(const bf16x8*)(As + (wr * 64 + mi * 16 + l15) * 32 + quad * 8);
        #pragma unroll
        for (int ni = 0; ni < 4; ++ni) bfr[ni] = *(const bf16x8*)(Bs + (wc * 64 + ni * 16 + l15) * 32 + quad * 8);
        #pragma unroll
        for (int mi = 0; mi < 4; ++mi)
            #pragma unroll
            for (int ni = 0; ni < 4; ++ni)
                acc[mi][ni] = __builtin_amdgcn_mfma_f32_16x16x32_bf16(af[mi], bfr[ni], acc[mi][ni], 0, 0, 0);
        __syncthreads();
    }

    // epilogue: acc (+bias, +act) -> Ct[128][136] bf16 (aliases As/Bs, safe after final barrier)
    int nb = nt * 128;
    #pragma unroll
    for (int mi = 0; mi < 4; ++mi)
        #pragma unroll
        for (int ni = 0; ni < 4; ++ni) {
            int ct = wc * 64 + ni * 16 + l15;        // tile-local col
            float bv = bias[nb + ct];
            #pragma unroll
            for (int r = 0; r < 4; ++r) {
                int rt = wr * 64 + mi * 16 + quad * 4 + r;   // tile-local row
                float v = acc[mi][ni][r] + bv;
                if (mode == 1) v = 0.5f * v * (1.0f + erff(v * 0.70710678118654752f));
                smem[rt * 136 + ct] = f2bf(v);
            }
        }
    __syncthreads();

    if (mode != 2 || nt < 6) {
        unsigned short* ob = out + (size_t)mt * 128 * ldout + nb;
        #pragma unroll
        for (int j = 0; j < 8; ++j) {
            int f16i = j * 256 + tid;
            int r = f16i >> 4;
            int c = (f16i & 15) * 8;
            *(uint4*)(ob + (size_t)r * ldout + c) = *(const uint4*)(smem + r * 136 + c);
        }
    } else {
        int cbase = nb - 768;
        #pragma unroll
        for (int j = 0; j < 64; ++j) {
            int fl = j * 256 + tid;
            int c = fl >> 7, r = fl & 127;
            int gr = mt * 128 + r;
            int win = gr / 49, tok = gr - win * 49;
            int rem = cbase + c;
            int head = rem >> 5, hd = rem & 31;
            vo[(((size_t)win * NH_ + head) * 32 + hd) * 64 + tok] = smem[r * 136 + c];
        }
    }
}

// ---------------- K4: windowed attention, one wave per (window, head) ----------------
__global__ __launch_bounds__(256) void k_attn(const unsigned short* __restrict__ qk,
        const unsigned short* __restrict__ vtb, const float* __restrict__ rpb,
        unsigned short* __restrict__ o) {
    __shared__ unsigned short P[4][64][72];
    int tid = threadIdx.x;
    int wave = tid >> 6, lane = tid & 63, l15 = lane & 15, quad = lane >> 4;
    int win = blockIdx.x / 3;
    int head = (blockIdx.x % 3) * 4 + wave;
    int wi = win & 63, wh = wi >> 3, ww = wi & 7;
    const unsigned short* qh = qk + (size_t)win * 49 * 768 + head * 32;
    const unsigned short* kh = qh + 384;
    const unsigned short* vh = vtb + ((size_t)win * NH_ + head) * (32 * 64);

    bf16x8 qf[4], kf[4];
    #pragma unroll
    for (int mi = 0; mi < 4; ++mi) qf[mi] = *(const bf16x8*)(qh + (size_t)(mi * 16 + l15) * 768 + quad * 8);
    #pragma unroll
    for (int ni = 0; ni < 4; ++ni) kf[ni] = *(const bf16x8*)(kh + (size_t)(ni * 16 + l15) * 768 + quad * 8);

    f32x4 z = {0.f, 0.f, 0.f, 0.f};
    f32x4 sc_[4][4];
    #pragma unroll
    for (int mi = 0; mi < 4; ++mi)
        #pragma unroll
        for (int ni = 0; ni < 4; ++ni)
            sc_[mi][ni] = __builtin_amdgcn_mfma_f32_16x16x32_bf16(qf[mi], kf[ni], z, 0, 0, 0);

    #pragma unroll
    for (int mi = 0; mi < 4; ++mi)
        #pragma unroll
        for (int r = 0; r < 4; ++r) {
            int qr = mi * 16 + quad * 4 + r;
            int qi = qr / 7, qj = qr - qi * 7;
            int rqh = (wh == 7) ? (qi < 4 ? 1 : 2) : 0;
            int rqw = (ww == 7) ? (qj < 4 ? 1 : 2) : 0;
            #pragma unroll
            for (int ni = 0; ni < 4; ++ni) {
                int kcol = ni * 16 + l15;
                float v = sc_[mi][ni][r] * SCALE_;
                if (qr < 49 && kcol < 49) {
                    int ki = kcol / 7, kj = kcol - ki * 7;
                    int idx = (qi - ki + 6) * 13 + (qj - kj + 6);
                    v += rpb[idx * NH_ + head];
                    int rkh = (wh == 7) ? (ki < 4 ? 1 : 2) : 0;
                    int rkw = (ww == 7) ? (kj < 4 ? 1 : 2) : 0;
                    if ((rqh * 3 + rqw) != (rkh * 3 + rkw)) v -= 100.0f;
                } else v = -1e30f;
                sc_[mi][ni][r] = v;
            }
        }

    float rinv[4][4];
    #pragma unroll
    for (int mi = 0; mi < 4; ++mi)
        #pragma unroll
        for (int r = 0; r < 4; ++r) {
            float m = fmaxf(fmaxf(sc_[mi][0][r], sc_[mi][1][r]), fmaxf(sc_[mi][2][r], sc_[mi][3][r]));
            #pragma unroll
            for (int d = 1; d < 16; d <<= 1) m = fmaxf(m, __shfl_xor(m, d));
            float sum = 0.f;
            #pragma unroll
            for (int ni = 0; ni < 4; ++ni) {
                float p = __expf(sc_[mi][ni][r] - m);
                sc_[mi][ni][r] = p;
                sum += p;
            }
            #pragma unroll
            for (int d = 1; d < 16; d <<= 1) sum += __shfl_xor(sum, d);
            rinv[mi][r] = 1.0f / sum;
        }

    #pragma unroll
    for (int mi = 0; mi < 4; ++mi)
        #pragma unroll
        for (int ni = 0; ni < 4; ++ni)
            #pragma unroll
            for (int r = 0; r < 4; ++r)
                P[wave][mi * 16 + quad * 4 + r][ni * 16 + l15] = f2bf(sc_[mi][ni][r]);
    __syncthreads();

    f32x4 oacc[4][2];
    #pragma unroll
    for (int mi = 0; mi < 4; ++mi) { oacc[mi][0] = z; oacc[mi][1] = z; }
    #pragma unroll
    for (int kt = 0; kt < 2; ++kt) {
        bf16x8 vf[2];
        #pragma unroll
        for (int n2 = 0; n2 < 2; ++n2)
            vf[n2] = *(const bf16x8*)(vh + (n2 * 16 + l15) * 64 + kt * 32 + quad * 8);
        #pragma unroll
        for (int mi = 0; mi < 4; ++mi) {
            bf16x8 pf = *(const bf16x8*)&P[wave][mi * 16 + l15][kt * 32 + quad * 8];
            #pragma unroll
            for (int n2 = 0; n2 < 2; ++n2)
                oacc[mi][n2] = __builtin_amdgcn_mfma_f32_16x16x32_bf16(pf, vf[n2], oacc[mi][n2], 0, 0, 0);
        }
    }

    #pragma unroll
    for (int mi = 0; mi < 4; ++mi)
        #pragma unroll
        for (int r = 0; r < 4; ++r) {
            int qr = mi * 16 + quad * 4 + r;
            if (qr < 49) {
                float s = rinv[mi][r];
                #pragma unroll
                for (int n2 = 0; n2 < 2; ++n2)
                    o[((size_t)win * 49 + qr) * C_ + head * 32 + n2 * 16 + l15] =
                        f2bf(oacc[mi][n2][r] * s);
            }
        }
}

// ---------------- K5: residual (in-place over xs) + LN2 ----------------
__global__ __launch_bounds__(256) void k_resid_ln2(const unsigned short* __restrict__ proj,
        unsigned short* __restrict__ xs, const float* __restrict__ g2,
        const float* __restrict__ b2, unsigned short* __restrict__ xn2) {
    int wave = threadIdx.x >> 6, lane = threadIdx.x & 63;
    size_t t = (size_t)blockIdx.x * 4 + wave;
    const unsigned short* pp = proj + t * C_;
    unsigned short* sp = xs + t * C_;
    float v[6];
    float sum = 0.f, sq = 0.f;
    #pragma unroll
    for (int j = 0; j < 6; ++j) {
        int c = j * 64 + lane;
        float val = bf2f(pp[c]) + bf2f(sp[c]);
        v[j] = val; sum += val; sq += val * val;
    }
    #pragma unroll
    for (int d = 1; d < 64; d <<= 1) { sum += __shfl_xor(sum, d); sq += __shfl_xor(sq, d); }
    float m = sum * (1.0f / C_);
    float rs = rsqrtf(sq * (1.0f / C_) - m * m + 1e-5f);
    #pragma unroll
    for (int j = 0; j < 6; ++j) {
        int c = j * 64 + lane;
        sp[c] = f2bf(v[j]);
        xn2[t * C_ + c] = f2bf((v[j] - m) * rs * g2[c] + b2[c]);
    }
}

// ---------------- K7: final (resid + mlp) + un-shift + transpose ----------------
__global__ __launch_bounds__(256) void k_final(const unsigned short* __restrict__ resid,
        const unsigned short* __restrict__ mlp, float* __restrict__ out) {
    __shared__ float T[32][33];
    int b = blockIdx.z, hw0 = blockIdx.y * 32, c0 = blockIdx.x * 32;
    int tid = threadIdx.x, lo = tid & 31, hi = tid >> 5;
    #pragma unroll
    for (int p = 0; p < 4; ++p) {
        int row = hi + p * 8;
        int hw = hw0 + row;
        int ho = hw / 56, wo = hw - ho * 56;
        int h = ho + 53; if (h >= 56) h -= 56;
        int w = wo + 53; if (w >= 56) w -= 56;
        size_t t1 = ((size_t)b * 64 + (h / 7) * 8 + (w / 7)) * 49 + (h % 7) * 7 + (w % 7);
        int c = c0 + lo;
        T[row][lo] = bf2f(resid[t1 * C_ + c]) + bf2f(mlp[t1 * C_ + c]);
    }
    __syncthreads();
    #pragma unroll
    for (int p = 0; p < 4; ++p) {
        int cr = hi + p * 8;
        out[((size_t)b * C_ + c0 + cr) * HW_ + hw0 + lo] = T[lo][cr];
    }
}

// ---------------- launch ----------------
extern "C" void kernel_launch(void* const* d_in, const int* in_sizes, int n_in,
                              void* d_out, int out_size, void* d_ws, size_t ws_size,
                              hipStream_t stream) {
    const float* x      = (const float*)d_in[0];
    const float* qkv_w  = (const float*)d_in[1];
    const float* qkv_b  = (const float*)d_in[2];
    const float* proj_w = (const float*)d_in[3];
    const float* proj_b = (const float*)d_in[4];
    const float* rpb    = (const float*)d_in[5];
    const float* n1w    = (const float*)d_in[6];
    const float* n1b    = (const float*)d_in[7];
    const float* n2w    = (const float*)d_in[8];
    const float* n2b    = (const float*)d_in[9];
    const float* fc1w   = (const float*)d_in[10];
    const float* fc1b   = (const float*)d_in[11];
    const float* fc2w   = (const float*)d_in[12];
    const float* fc2b   = (const float*)d_in[13];
    float* out = (float*)d_out;
    (void)ws_size; (void)in_sizes; (void)n_in; (void)out_size;

    char* ws = (char*)d_ws;
    size_t off = 0;
    auto take = [&](size_t bytes) -> char* {
        char* p = ws + off;
        off = (off + bytes + 255) & ~((size_t)255);
        return p;
    };
    const size_t SZ_TC = (size_t)NTOK * C_ * 2;
    unsigned short* xs   = (unsigned short*)take(SZ_TC);
    unsigned short* bufB = (unsigned short*)take(SZ_TC);
    unsigned short* bufC = (unsigned short*)take((size_t)(NTOK + 16) * 768 * 2);
    unsigned short* bufD = (unsigned short*)take((size_t)50176 * 1536 * 2);
    unsigned short* wqkv = (unsigned short*)take((size_t)1152 * 384 * 2);
    unsigned short* wprj = (unsigned short*)take((size_t)384 * 384 * 2);
    unsigned short* wfc1 = (unsigned short*)take((size_t)1536 * 384 * 2);
    unsigned short* wfc2 = (unsigned short*)take((size_t)384 * 1536 * 2);

    unsigned short* xw  = bufB;
    unsigned short* ob  = bufB;
    unsigned short* mlp = bufB;
    unsigned short* qkb = bufC;
    unsigned short* prj = bufC;
    unsigned short* xn2 = bufC + (SZ_TC / 2);
    unsigned short* vt  = bufD;
    unsigned short* hid = bufD;

    k_wt<<<(1152 * 384 + 255) / 256, 256, 0, stream>>>(qkv_w, wqkv, 384, 1152);
    k_wt<<<(384 * 384 + 255) / 256, 256, 0, stream>>>(proj_w, wprj, 384, 384);
    k_wt<<<(1536 * 384 + 255) / 256, 256, 0, stream>>>(fc1w, wfc1, 384, 1536);
    k_wt<<<(384 * 1536 + 255) / 256, 256, 0, stream>>>(fc2w, wfc2, 1536, 384);

    k_ln1<<<32 * 98, 256, 0, stream>>>(x, n1w, n1b, xw, xs);

    k_gemm<<<784 * 9, 256, 0, stream>>>(xw, wqkv, qkv_b, qkb, 9, 384, 768, 2, vt);
    k_attn<<<NWIN * 3, 256, 0, stream>>>(qkb, vt, rpb, ob);
    k_gemm<<<784 * 3, 256, 0, stream>>>(ob, wprj, proj_b, prj, 3, 384, 384, 0, nullptr);
    k_resid_ln2<<<NTOK / 4, 256, 0, stream>>>(prj, xs, n2w, n2b, xn2);

    const int CH = 50176;
    for (int i = 0; i < 2; ++i) {
        k_gemm<<<392 * 12, 256, 0, stream>>>(xn2 + (size_t)i * CH * 384, wfc1, fc1b,
                hid, 12, 384, 1536, 1, nullptr);
        k_gemm<<<392 * 3, 256, 0, stream>>>(hid, wfc2, fc2b,
                mlp + (size_t)i * CH * 384, 3, 1536, 384, 0, nullptr);
    }
    k_final<<<dim3(12, 98, 32), 256, 0, stream>>>(xs, mlp, out);
}